// Round 1
// baseline (314.651 us; speedup 1.0000x reference)
//
#include <hip/hip_runtime.h>

#define NPT   4096
#define KNN_K 16
#define EPSV  1e-5f

// ---- ws float layout ----
#define W0T_OFF 0                  // [67][64] folded (rows 0..63 = points cols, 64..66 = xyz cols)
#define B0_OFF  4288               // [64]
#define W1T_OFF 4352               // [64][64]  (ic-major)
#define B1_OFF  8448               // [64]
#define W2T_OFF 8512               // [64][128] (ic-major)
#define B2_OFF  16704              // [128]
#define IDX_OFF 16832              // int[4*4096*16]
#define XYZ4_OFF 278976            // float4[16384]
#define P_OFF   344512             // float[16384][64]  P = W0p*pts + W0x*xyz + b0
#define Q_OFF   1393088            // float[16384][64]  Q = W0x*xyz

typedef unsigned long long ull;

__global__ void prep_kernel(
    const float* __restrict__ xyz,
    const float* __restrict__ w0, const float* __restrict__ b0, const float* __restrict__ g0,
    const float* __restrict__ be0, const float* __restrict__ rm0, const float* __restrict__ rv0,
    const float* __restrict__ w1, const float* __restrict__ b1, const float* __restrict__ g1,
    const float* __restrict__ be1, const float* __restrict__ rm1, const float* __restrict__ rv1,
    const float* __restrict__ w2, const float* __restrict__ b2, const float* __restrict__ g2,
    const float* __restrict__ be2, const float* __restrict__ rm2, const float* __restrict__ rv2,
    float* __restrict__ ws) {
  int blk = blockIdx.x;
  if (blk < 64) {                        // xyz -> (x,y,z,sq), exact ref arithmetic for knn
    int i = blk * 256 + threadIdx.x;
    const float* p = xyz + i * 3;
    float x = p[0], y = p[1], z = p[2];
    float sq = __fadd_rn(__fadd_rn(__fmul_rn(x, x), __fmul_rn(y, y)), __fmul_rn(z, z));
    ((float4*)(ws + XYZ4_OFF))[i] = make_float4(x, y, z, sq);
    return;
  }
  int i = (blk - 64) * 256 + threadIdx.x;
  if (i < 4288) {                        // w0t: [ic'][oc]
    int oc = i & 63, icp = i >> 6;
    int col = (icp < 64) ? (icp + 3) : (icp - 64);
    float s = g0[oc] * rsqrtf(rv0[oc] + EPSV);
    ws[W0T_OFF + i] = w0[oc * 67 + col] * s;
  } else if (i < 4352) {
    int oc = i - 4288;
    float s = g0[oc] * rsqrtf(rv0[oc] + EPSV);
    ws[i] = (b0[oc] - rm0[oc]) * s + be0[oc];
  } else if (i < 8448) {
    int j = i - 4352; int oc = j & 63, ic = j >> 6;
    float s = g1[oc] * rsqrtf(rv1[oc] + EPSV);
    ws[i] = w1[oc * 64 + ic] * s;
  } else if (i < 8512) {
    int oc = i - 8448;
    float s = g1[oc] * rsqrtf(rv1[oc] + EPSV);
    ws[i] = (b1[oc] - rm1[oc]) * s + be1[oc];
  } else if (i < 16704) {
    int j = i - 8512; int ic = j >> 7, oc = j & 127;
    float s = g2[oc] * rsqrtf(rv2[oc] + EPSV);
    ws[i] = w2[oc * 64 + ic] * s;       // w2t [ic][oc]
  } else if (i < 16832) {
    int oc = i - 16704;
    float s = g2[oc] * rsqrtf(rv2[oc] + EPSV);
    ws[i] = (b2[oc] - rm2[oc]) * s + be2[oc];
  }
}

// P/Q precompute: wave = one point, lane = oc. w0t reads coalesced, points reads
// wave-uniform (scalarized). 70M MAC total.
__global__ __launch_bounds__(256) void pq_kernel(const float* __restrict__ xyz,
                                                 const float* __restrict__ points,
                                                 float* __restrict__ ws) {
  int tid = threadIdx.x;
  int oc = tid & 63;
  int i = blockIdx.x * 4 + (tid >> 6);
  const float* w0t = ws + W0T_OFF;
  float x = xyz[i * 3], y = xyz[i * 3 + 1], z = xyz[i * 3 + 2];
  float qacc = w0t[64 * 64 + oc] * x;
  qacc = fmaf(w0t[65 * 64 + oc], y, qacc);
  qacc = fmaf(w0t[66 * 64 + oc], z, qacc);
  float acc = ws[B0_OFF + oc] + qacc;
  const float* prow = points + (size_t)i * 64;
#pragma unroll 4
  for (int c = 0; c < 64; ++c) acc = fmaf(w0t[c * 64 + oc], prow[c], acc);
  ws[P_OFF + (size_t)i * 64 + oc] = acc;
  ws[Q_OFF + (size_t)i * 64 + oc] = qacc;
}

__device__ __forceinline__ ull minu64(ull a, ull b) { return a < b ? a : b; }
__device__ __forceinline__ ull maxu64(ull a, ull b) { return a > b ? a : b; }

__device__ __forceinline__ ull bitonic_sort64(ull v, int lane) {
#pragma unroll
  for (int k = 2; k <= 64; k <<= 1) {
#pragma unroll
    for (int j = k >> 1; j > 0; j >>= 1) {
      ull o = __shfl_xor(v, j);
      bool lower = (lane & j) == 0;
      bool up = (lane & k) == 0;
      v = (lower == up) ? minu64(v, o) : maxu64(v, o);
    }
  }
  return v;
}

__device__ __forceinline__ ull bitonic_merge64(ull v, int lane) {
#pragma unroll
  for (int j = 32; j > 0; j >>= 1) {
    ull o = __shfl_xor(v, j);
    v = ((lane & j) == 0) ? minu64(v, o) : maxu64(v, o);
  }
  return v;
}

// KNN (unchanged): wave/query threshold-filter + bitonic flush.
__global__ __launch_bounds__(256) void knn_kernel(const float4* __restrict__ cand4,
                                                  int* __restrict__ knnOut) {
  __shared__ __align__(16) float4 tile[1024];
  __shared__ ull buf[4][128];
  int tid = threadIdx.x;
  int lane = tid & 63, w = tid >> 6;
  int b = blockIdx.x >> 10;
  int n = ((blockIdx.x & 1023) << 2) + w;
  const float4* cb = cand4 + b * NPT;

  float4 q = cb[n];
  ull R = ~0ull;
  ull thresh = ~0ull;
  int cnt = 0;
  ull ltmask = (lane == 0) ? 0ull : (~0ull >> (64 - lane));

#pragma unroll 1
  for (int t = 0; t < 4; ++t) {
    __syncthreads();
#pragma unroll
    for (int j = 0; j < 4; ++j) tile[j * 256 + tid] = cb[t * 1024 + j * 256 + tid];
    __syncthreads();
#pragma unroll 1
    for (int i = 0; i < 16; ++i) {
      int ml = (i << 6) + lane;
      float4 c = tile[ml];
      float dot = __fadd_rn(__fadd_rn(__fmul_rn(q.x, c.x), __fmul_rn(q.y, c.y)),
                            __fmul_rn(q.z, c.z));
      float d2 = __fsub_rn(__fadd_rn(q.w, c.w), __fmul_rn(2.0f, dot));
      unsigned bits = __float_as_uint(d2);
      unsigned fk = bits ^ (0x80000000u | (unsigned)((int)bits >> 31));
      ull key = ((ull)fk << 32) | (unsigned)((t << 10) + ml);
      bool pred = key < thresh;
      ull mask = __ballot(pred);
      if (mask) {
        int pos = cnt + __popcll(mask & ltmask);
        if (pred) buf[w][pos] = key;
        cnt += __popcll(mask);
        if (cnt >= 64) {
          ull v = buf[w][lane];
          v = bitonic_sort64(v, lane);
          ull vr = __shfl(v, 63 - lane);
          R = minu64(R, vr);
          R = bitonic_merge64(R, lane);
          thresh = __shfl(R, 15);
          cnt -= 64;
          if (lane < cnt) {
            ull tmp = buf[w][64 + lane];
            buf[w][lane] = tmp;
          }
        }
      }
    }
  }
  {
    ull v = (lane < cnt) ? buf[w][lane] : ~0ull;
    v = bitonic_sort64(v, lane);
    ull vr = __shfl(v, 63 - lane);
    R = minu64(R, vr);
    R = bitonic_merge64(R, lane);
  }
  if (lane < KNN_K)
    knnOut[(b * NPT + n) * KNN_K + lane] = (int)(unsigned)(R & 0xFFFFFFFFull);
}

// MLP v3: lane = pair (wave = 4 queries x 16 k = 64 pairs). Activations in a
// per-wave LDS tile A[ic][pair]; weights read via wave-uniform addresses ->
// scalar s_load + v_fmac(acc, s_w, v_a). Inner loop per ic: 1 conflict-free
// ds_read_b32 (reused 64x) + 64 FMA. No __syncthreads, no weight staging, no
// bank conflicts. h1 round-trips through the same LDS tile to keep all
// register-array indexing static (no scratch).
__global__ __launch_bounds__(256) void mlp_kernel(
    const float* __restrict__ wbuf, const int* __restrict__ knn,
    float* __restrict__ out) {
  __shared__ float Ash[4][64 * 64];   // 64 KB: per-wave [ic][pair] tile
  int tid = threadIdx.x;
  int lane = tid & 63, w = tid >> 6;
  float* Aw = Ash[w];

  int q = blockIdx.x * 16 + w * 4 + (lane >> 4);   // flat query in [0, B*N)
  int k = lane & 15;
  int src = knn[q * KNN_K + k];                     // per-batch index
  int srow = (q & ~(NPT - 1)) + src;                // flat source row

  // ---- h0 = relu(P[src] - Q[q]) -> A[ic][pair] ----
  {
    const float4* Pp = (const float4*)(wbuf + P_OFF + (size_t)srow * 64);
    const float4* Qp = (const float4*)(wbuf + Q_OFF + (size_t)q * 64);
#pragma unroll
    for (int j = 0; j < 16; ++j) {
      float4 pv = Pp[j];
      float4 qv = Qp[j];
      int ic = j * 4;
      Aw[(ic + 0) * 64 + lane] = fmaxf(pv.x - qv.x, 0.0f);
      Aw[(ic + 1) * 64 + lane] = fmaxf(pv.y - qv.y, 0.0f);
      Aw[(ic + 2) * 64 + lane] = fmaxf(pv.z - qv.z, 0.0f);
      Aw[(ic + 3) * 64 + lane] = fmaxf(pv.w - qv.w, 0.0f);
    }
  }
  __builtin_amdgcn_wave_barrier();   // same-wave LDS RAW: in-order DS pipe

  // ---- layer 1: h1 = relu(W1 h0) ----
  float h1[64];
#pragma unroll
  for (int j = 0; j < 64; ++j) h1[j] = wbuf[B1_OFF + j];   // uniform -> s_load
  {
    const float* w1 = wbuf + W1T_OFF;
#pragma unroll 1
    for (int ic = 0; ic < 64; ++ic) {
      float a = Aw[ic * 64 + lane];            // ds_read_b32, 2-way (free)
      const float* wr = w1 + ic * 64;          // wave-uniform row
#pragma unroll
      for (int j = 0; j < 64; ++j) h1[j] = fmaf(a, wr[j], h1[j]);
    }
  }
  __builtin_amdgcn_wave_barrier();
#pragma unroll
  for (int j = 0; j < 64; ++j) Aw[j * 64 + lane] = fmaxf(h1[j], 0.0f);
  __builtin_amdgcn_wave_barrier();

  // ---- layer 2 (two 64-oc passes) + relu + max over k + store ----
  const float* w2 = wbuf + W2T_OFF;
  float* obase = out + (size_t)q * 128;
#pragma unroll 1
  for (int pass = 0; pass < 2; ++pass) {
    float acc[64];
#pragma unroll
    for (int j = 0; j < 64; ++j) acc[j] = wbuf[B2_OFF + pass * 64 + j];
#pragma unroll 1
    for (int ic = 0; ic < 64; ++ic) {
      float a = Aw[ic * 64 + lane];
      const float* wr = w2 + ic * 128 + pass * 64;   // wave-uniform row
#pragma unroll
      for (int j = 0; j < 64; ++j) acc[j] = fmaf(a, wr[j], acc[j]);
    }
#pragma unroll
    for (int j = 0; j < 64; ++j) {
      float v = fmaxf(acc[j], 0.0f);
      v = fmaxf(v, __shfl_xor(v, 1));
      v = fmaxf(v, __shfl_xor(v, 2));
      v = fmaxf(v, __shfl_xor(v, 4));
      v = fmaxf(v, __shfl_xor(v, 8));
      acc[j] = v;
    }
    if (k == 0) {
      float4* o4 = (float4*)(obase + pass * 64);
#pragma unroll
      for (int j = 0; j < 16; ++j)
        o4[j] = make_float4(acc[4 * j], acc[4 * j + 1], acc[4 * j + 2], acc[4 * j + 3]);
    }
  }
}

extern "C" void kernel_launch(void* const* d_in, const int* in_sizes, int n_in,
                              void* d_out, int out_size, void* d_ws, size_t ws_size,
                              hipStream_t stream) {
  const float* xyz    = (const float*)d_in[0];
  const float* points = (const float*)d_in[1];
  float* wsF = (float*)d_ws;
  int* idxBuf = (int*)(wsF + IDX_OFF);
  const float4* cand4 = (const float4*)(wsF + XYZ4_OFF);

  prep_kernel<<<130, 256, 0, stream>>>(
      xyz,
      (const float*)d_in[2],  (const float*)d_in[3],  (const float*)d_in[4],
      (const float*)d_in[5],  (const float*)d_in[6],  (const float*)d_in[7],
      (const float*)d_in[8],  (const float*)d_in[9],  (const float*)d_in[10],
      (const float*)d_in[11], (const float*)d_in[12], (const float*)d_in[13],
      (const float*)d_in[14], (const float*)d_in[15], (const float*)d_in[16],
      (const float*)d_in[17], (const float*)d_in[18], (const float*)d_in[19],
      wsF);
  pq_kernel<<<4096, 256, 0, stream>>>(xyz, points, wsF);
  knn_kernel<<<4096, 256, 0, stream>>>(cand4, idxBuf);
  mlp_kernel<<<1024, 256, 0, stream>>>(wsF, idxBuf, (float*)d_out);
}